// Round 4
// baseline (545.482 us; speedup 1.0000x reference)
//
#include <hip/hip_runtime.h>

#define B_ 4096
#define T_ 512
#define F_ 8
#define H_ 16

typedef __fp16 f16;
typedef __fp16 f16x2 __attribute__((ext_vector_type(2)));
typedef __fp16 f16x4 __attribute__((ext_vector_type(4)));
typedef float f32x4 __attribute__((ext_vector_type(4)));

#define LOG2E 1.442695041f
#define N2LOG2E (-2.885390082f)

__device__ __forceinline__ float sigf(float x) {
    return __builtin_amdgcn_rcpf(1.0f + __builtin_amdgcn_exp2f(-LOG2E * x));
}
__device__ __forceinline__ float tanh_f(float x) {
    return __builtin_fmaf(2.0f,
        __builtin_amdgcn_rcpf(1.0f + __builtin_amdgcn_exp2f(N2LOG2E * x)), -1.0f);
}

__device__ __forceinline__ f16x4 mk4(f16x2 a, f16x2 b) {
    f16x4 r; r[0] = a[0]; r[1] = a[1]; r[2] = b[0]; r[3] = b[1]; return r;
}

__device__ __forceinline__ f32x4 mfma16(f16x4 a, f16x4 b, f32x4 c) {
    return __builtin_amdgcn_mfma_f32_16x16x16f16(a, b, c, 0, 0, 0);
}

// split 4 f32 into f16 hi + f16 residual lo (W ~= hi + lo to ~2^-22 rel)
__device__ __forceinline__ void split_hl(f32x4 w, f16x4& hi, f16x4& lo) {
    f16x2 h0 = __builtin_amdgcn_cvt_pkrtz(w[0], w[1]);
    f16x2 h1 = __builtin_amdgcn_cvt_pkrtz(w[2], w[3]);
    f16x2 l0 = __builtin_amdgcn_cvt_pkrtz(w[0] - (float)h0[0], w[1] - (float)h0[1]);
    f16x2 l1 = __builtin_amdgcn_cvt_pkrtz(w[2] - (float)h1[0], w[3] - (float)h1[1]);
    hi = mk4(h0, h1); lo = mk4(l0, l1);
}

// MFMA-based LSTM autoencoder.
// One wave serves 4 chains (cols 0..3 of the 16-col MFMA N dim; cols 4..15 are
// bounded garbage, never stored). 1024 waves -> 1 wave/SIMD, all SIMDs busy.
// Gate rows (4H=64) = 4 MFMA row-blocks of 16 (i,f,g,o). Key layout identity
// for 16x16x16: D(row=4q+e, col=lane&15) == B(k=4q+e, col=lane&15), so each
// lane's updated h feeds the next step's B operand with no cross-lane moves.
// Precision: hi/lo f16 splitting of W, h, x (drop lo*lo) -> fp32-grade matmul.
__global__ __launch_bounds__(256, 1) void lstm_ae_kernel(
    const float* __restrict__ x,
    const float* __restrict__ eWih, const float* __restrict__ eWhh,
    const float* __restrict__ ebih, const float* __restrict__ ebhh,
    const float* __restrict__ dWih, const float* __restrict__ dWhh,
    const float* __restrict__ dbih, const float* __restrict__ dbhh,
    const float* __restrict__ oW,   const float* __restrict__ ob,
    float* __restrict__ out)
{
    const int l  = threadIdx.x & 63;
    const int wv = threadIdx.x >> 6;      // wave in block, 0..3
    const int n  = l & 15;                // MFMA col (chain) / A-frag row m
    const int q  = l >> 4;                // 0..3
    const int b0 = (blockIdx.x * 4 + wv) * 4;   // 4 valid chains b0..b0+3
    const bool ldx = (n < 4);
    const f16x4 zf = {};

    // ---------------- encoder fragments ----------------
    f16x4 ehh_hi[4], ehh_lo[4], eih[4], eih_hi[4];
    f32x4 biasE[4];
#pragma unroll
    for (int blk = 0; blk < 4; ++blk) {
        const int m = blk * 16 + n;
        f32x4 w = *(const f32x4*)(eWhh + m * 16 + 4 * q);
        split_hl(w, ehh_hi[blk], ehh_lo[blk]);
        // A_x = [Wih_hi (k0-7) | Wih_lo (k8-15)]; B_x = [x_hi; x_hi]
        f32x4 wx = *(const f32x4*)(eWih + m * 8 + (q & 1) * 4);
        f16x4 xh, xl; split_hl(wx, xh, xl);
        eih[blk]    = (q < 2) ? xh : xl;
        eih_hi[blk] = (q < 2) ? xh : zf;  // for the x_lo residual term
        f32x4 b1 = *(const f32x4*)(ebih + blk * 16 + 4 * q);
        f32x4 b2 = *(const f32x4*)(ebhh + blk * 16 + 4 * q);
        biasE[blk] = b1 + b2;
    }

    float cst[4] = {0.0f, 0.0f, 0.0f, 0.0f};
    f16x4 Bh_hi = zf, Bh_lo = zf;

    // x ring buffer, prefetch depth 3 (~1000cy of HBM latency coverage)
    const float* xb = x + (size_t)(b0 + n) * (T_ * F_) + (q & 1) * 4;
    f32x4 xr[4] = {};
    if (ldx) {
        xr[0] = *(const f32x4*)(xb + 0 * F_);
        xr[1] = *(const f32x4*)(xb + 1 * F_);
        xr[2] = *(const f32x4*)(xb + 2 * F_);
    }

    // ---------------- encoder ----------------
    for (int t = 0; t < T_; t += 4) {
#pragma unroll
        for (int u = 0; u < 4; ++u) {
            const int tt = t + u;
            f32x4 xv = xr[u];
            if (ldx && tt + 3 < T_)
                xr[(u + 3) & 3] = *(const f32x4*)(xb + (tt + 3) * F_);
            f16x2 xh0 = __builtin_amdgcn_cvt_pkrtz(xv[0], xv[1]);
            f16x2 xh1 = __builtin_amdgcn_cvt_pkrtz(xv[2], xv[3]);
            f16x4 Bx = mk4(xh0, xh1);
            f16x2 xl0 = __builtin_amdgcn_cvt_pkrtz(xv[0] - (float)xh0[0],
                                                   xv[1] - (float)xh0[1]);
            f16x2 xl1 = __builtin_amdgcn_cvt_pkrtz(xv[2] - (float)xh1[0],
                                                   xv[3] - (float)xh1[1]);
            f16x4 Bxl = mk4(xl0, xl1);

            f32x4 acc[4];
#pragma unroll
            for (int blk = 0; blk < 4; ++blk)
                acc[blk] = mfma16(eih[blk], Bx, biasE[blk]);       // W_ih·x_hi
#pragma unroll
            for (int blk = 0; blk < 4; ++blk)
                acc[blk] = mfma16(eih_hi[blk], Bxl, acc[blk]);     // Wih_hi·x_lo
#pragma unroll
            for (int blk = 0; blk < 4; ++blk)
                acc[blk] = mfma16(ehh_hi[blk], Bh_hi, acc[blk]);
#pragma unroll
            for (int blk = 0; blk < 4; ++blk)
                acc[blk] = mfma16(ehh_lo[blk], Bh_hi, acc[blk]);
#pragma unroll
            for (int blk = 0; blk < 4; ++blk)
                acc[blk] = mfma16(ehh_hi[blk], Bh_lo, acc[blk]);

            float hv[4];
#pragma unroll
            for (int e = 0; e < 4; ++e) {
                float gi = sigf(acc[0][e]);
                float gf = sigf(acc[1][e]);
                float gg = tanh_f(acc[2][e]);
                float go = sigf(acc[3][e]);
                cst[e] = __builtin_fmaf(gf, cst[e], gi * gg);
                hv[e]  = go * tanh_f(cst[e]);
            }
            f16x2 p0 = __builtin_amdgcn_cvt_pkrtz(hv[0], hv[1]);
            f16x2 p1 = __builtin_amdgcn_cvt_pkrtz(hv[2], hv[3]);
            Bh_hi = mk4(p0, p1);
            f16x2 r0 = __builtin_amdgcn_cvt_pkrtz(hv[0] - (float)p0[0],
                                                  hv[1] - (float)p0[1]);
            f16x2 r1 = __builtin_amdgcn_cvt_pkrtz(hv[2] - (float)p1[0],
                                                  hv[3] - (float)p1[1]);
            Bh_lo = mk4(r0, r1);
        }
    }

    // ------------- decoder fragments + constant input projection -----------
    f16x4 dhh_hi[4], dhh_lo[4], oWhi, oWlo;
    f32x4 xpC[4], obC = {};
#pragma unroll
    for (int blk = 0; blk < 4; ++blk) {
        const int m = blk * 16 + n;
        f32x4 w = *(const f32x4*)(dWhh + m * 16 + 4 * q);
        split_hl(w, dhh_hi[blk], dhh_lo[blk]);
        f32x4 wi = *(const f32x4*)(dWih + m * 16 + 4 * q);
        f16x4 dih_hi, dih_lo; split_hl(wi, dih_hi, dih_lo);
        f32x4 bb = *(const f32x4*)(dbih + blk * 16 + 4 * q);
        f32x4 b2 = *(const f32x4*)(dbhh + blk * 16 + 4 * q);
        bb = bb + b2;
        f32x4 p = mfma16(dih_hi, Bh_hi, bb);    // xp = dWih·hT + bias (f32-grade)
        p = mfma16(dih_lo, Bh_hi, p);
        p = mfma16(dih_hi, Bh_lo, p);
        xpC[blk] = p;
    }
    {
        f32x4 wo = {};
        if (n < 8) wo = *(const f32x4*)(oW + n * 16 + 4 * q);
        split_hl(wo, oWhi, oWlo);               // rows 8..15 zero -> D rows = C
        if (q < 2) obC = *(const f32x4*)(ob + 4 * q);
    }

    cst[0] = cst[1] = cst[2] = cst[3] = 0.0f;
    Bh_hi = zf; Bh_lo = zf;

    const size_t obase = (size_t)(b0 + n) * (T_ * F_) + 4 * q;
    const bool stv = (n < 4) && (q < 2);

    // ---------------- decoder + fused output projection ----------------
#pragma unroll 2
    for (int t = 0; t < T_; ++t) {
        f32x4 acc[4];
#pragma unroll
        for (int blk = 0; blk < 4; ++blk)
            acc[blk] = mfma16(dhh_hi[blk], Bh_hi, xpC[blk]);
#pragma unroll
        for (int blk = 0; blk < 4; ++blk)
            acc[blk] = mfma16(dhh_lo[blk], Bh_hi, acc[blk]);
#pragma unroll
        for (int blk = 0; blk < 4; ++blk)
            acc[blk] = mfma16(dhh_hi[blk], Bh_lo, acc[blk]);

        float hv[4];
#pragma unroll
        for (int e = 0; e < 4; ++e) {
            float gi = sigf(acc[0][e]);
            float gf = sigf(acc[1][e]);
            float gg = tanh_f(acc[2][e]);
            float go = sigf(acc[3][e]);
            cst[e] = __builtin_fmaf(gf, cst[e], gi * gg);
            hv[e]  = go * tanh_f(cst[e]);
        }
        f16x2 p0 = __builtin_amdgcn_cvt_pkrtz(hv[0], hv[1]);
        f16x2 p1 = __builtin_amdgcn_cvt_pkrtz(hv[2], hv[3]);
        Bh_hi = mk4(p0, p1);
        f16x2 r0 = __builtin_amdgcn_cvt_pkrtz(hv[0] - (float)p0[0],
                                              hv[1] - (float)p0[1]);
        f16x2 r1 = __builtin_amdgcn_cvt_pkrtz(hv[2] - (float)p1[0],
                                              hv[3] - (float)p1[1]);
        Bh_lo = mk4(r0, r1);

        f32x4 oacc = mfma16(oWhi, Bh_hi, obC);  // out = oW·h + ob, fused
        oacc = mfma16(oWlo, Bh_hi, oacc);
        oacc = mfma16(oWhi, Bh_lo, oacc);
        if (stv) *(f32x4*)(out + obase + (size_t)t * F_) = oacc;
    }
}

extern "C" void kernel_launch(void* const* d_in, const int* in_sizes, int n_in,
                              void* d_out, int out_size, void* d_ws, size_t ws_size,
                              hipStream_t stream) {
    (void)in_sizes; (void)n_in; (void)d_ws; (void)ws_size; (void)out_size;
    lstm_ae_kernel<<<dim3(B_ / 16), dim3(256), 0, stream>>>(
        (const float*)d_in[0],
        (const float*)d_in[1], (const float*)d_in[2],
        (const float*)d_in[3], (const float*)d_in[4],
        (const float*)d_in[5], (const float*)d_in[6],
        (const float*)d_in[7], (const float*)d_in[8],
        (const float*)d_in[9], (const float*)d_in[10],
        (float*)d_out);
}